// Round 4
// baseline (62.771 us; speedup 1.0000x reference)
//
#include <hip/hip_runtime.h>
#include <math.h>

#define NBATCH 4
#define NPTS   8192
#define TPB    512
#define NWAVE  (TPB / 64)                 // 8 waves
#define QPB    1024                       // queries per block
#define QPT    16                         // queries per lane (QPB = 64*QPT)
#define QTILES (NPTS / QPB)               // 8 query tiles
#define PSPLIT 4                          // point-set split across blocks
#define PPB    (NPTS / PSPLIT)            // 2048 points per block
#define SLICE  (PPB / NWAVE)              // 256 points per wave
#define NBLK   (2 * NBATCH * QTILES * PSPLIT)  // 256 blocks = 1/CU

typedef float v2f __attribute__((ext_vector_type(2)));
typedef float v4f __attribute__((ext_vector_type(4)));

struct PG {  // one 8-point group, SoA components (-2x,-2y,-2z,norm)
    v4f x0, x1, y0, y1, z0, z1, w0, w1;
};

__device__ __forceinline__ PG loadpg(const float* sx, const float* sy,
                                     const float* sz, const float* sw, int i) {
    PG g;
    g.x0 = *(const v4f*)&sx[i]; g.x1 = *(const v4f*)&sx[i + 4];
    g.y0 = *(const v4f*)&sy[i]; g.y1 = *(const v4f*)&sy[i + 4];
    g.z0 = *(const v4f*)&sz[i]; g.z1 = *(const v4f*)&sz[i + 4];
    g.w0 = *(const v4f*)&sw[i]; g.w1 = *(const v4f*)&sw[i + 4];
    return g;
}

// 3 v_pk_fma_f32 + 1 v_min3_f32 per (2 points, 1 query) = 2.0 VALU/pair.
__device__ __forceinline__ void comp(const PG& g, const v2f* qxv,
                                     const v2f* qyv, const v2f* qzv, float* m) {
    v2f xp[4] = { g.x0.lo, g.x0.hi, g.x1.lo, g.x1.hi };
    v2f yp[4] = { g.y0.lo, g.y0.hi, g.y1.lo, g.y1.hi };
    v2f zp[4] = { g.z0.lo, g.z0.hi, g.z1.lo, g.z1.hi };
    v2f wp[4] = { g.w0.lo, g.w0.hi, g.w1.lo, g.w1.hi };
    #pragma unroll
    for (int k = 0; k < QPT; ++k) {
        #pragma unroll
        for (int gg = 0; gg < 4; ++gg) {
            v2f d = __builtin_elementwise_fma(qxv[k], xp[gg],
                    __builtin_elementwise_fma(qyv[k], yp[gg],
                    __builtin_elementwise_fma(qzv[k], zp[gg], wp[gg])));
            m[k] = fminf(fminf(m[k], d.x), d.y);   // -> v_min3_f32
        }
    }
}

// Block = (dir, batch, 1024-query tile, quarter of the point set).
// 2048 points staged in LDS SoA (32 KiB); wave w scans its 256-point slice
// for all 1024 queries (16/lane). All lanes read the same LDS address ->
// broadcast. Register A/B prefetch hides DS latency at 2 waves/SIMD.
// Writes qn + partial-min per query to ws; finalize min-combines PSPLIT
// blocks, thresholds, sums.
__global__ __launch_bounds__(TPB, 2) void chamfer_main(
    const float* __restrict__ xyz1,
    const float* __restrict__ xyz2,
    float* __restrict__ ws_part)
{
    __shared__ float sx[PPB] __attribute__((aligned(16)));
    __shared__ float sy[PPB] __attribute__((aligned(16)));
    __shared__ float sz[PPB] __attribute__((aligned(16)));
    __shared__ float sw[PPB] __attribute__((aligned(16)));
    __shared__ float part[NWAVE][QPB];      // 32 KiB slice partial mins

    const int bid  = blockIdx.x;
    const int ph   = bid & (PSPLIT - 1);
    const int r1   = bid >> 2;
    const int tile = r1 & (QTILES - 1);
    const int r2   = r1 >> 3;
    const int b    = r2 & (NBATCH - 1);
    const int dir  = r2 >> 2;               // 0: q=xyz1,r=xyz2; 1: swapped

    const float* q  = (dir == 0 ? xyz1 : xyz2) + (size_t)b * NPTS * 3;
    const float* rp = (dir == 0 ? xyz2 : xyz1) + (size_t)b * NPTS * 3
                      + (size_t)ph * PPB * 3;

    for (int i = threadIdx.x; i < PPB; i += TPB) {
        float x = rp[3 * i + 0], y = rp[3 * i + 1], z = rp[3 * i + 2];
        sx[i] = -2.0f * x;
        sy[i] = -2.0f * y;
        sz[i] = -2.0f * z;
        sw[i] = x * x + y * y + z * z;
    }
    __syncthreads();

    const int lane = threadIdx.x & 63;
    const int w    = threadIdx.x >> 6;
    const int q0   = tile * QPB + lane * QPT;

    v2f qxv[QPT], qyv[QPT], qzv[QPT];
    float m[QPT];
    #pragma unroll
    for (int k = 0; k < QPT; ++k) {
        float Qx = q[3 * (q0 + k) + 0];
        float Qy = q[3 * (q0 + k) + 1];
        float Qz = q[3 * (q0 + k) + 2];
        qxv[k] = (v2f){ Qx, Qx };
        qyv[k] = (v2f){ Qy, Qy };
        qzv[k] = (v2f){ Qz, Qz };
        m[k]   = INFINITY;
    }

    const int base = w * SLICE;
    PG A = loadpg(sx, sy, sz, sw, base + 0);
    PG B = loadpg(sx, sy, sz, sw, base + 8);
    #pragma unroll 1
    for (int j = 0; j < SLICE - 16; j += 16) {
        comp(A, qxv, qyv, qzv, m);
        A = loadpg(sx, sy, sz, sw, base + j + 16);
        comp(B, qxv, qyv, qzv, m);
        B = loadpg(sx, sy, sz, sw, base + j + 24);
    }
    comp(A, qxv, qyv, qzv, m);
    comp(B, qxv, qyv, qzv, m);

    #pragma unroll
    for (int k = 0; k < QPT; ++k)
        part[w][lane * QPT + k] = m[k];
    __syncthreads();

    // Combine 8 slice-mins per query, add qn, write block partial to ws.
    for (int ql = threadIdx.x; ql < QPB; ql += TPB) {
        float mv = part[0][ql];
        #pragma unroll
        for (int s = 1; s < NWAVE; ++s) mv = fminf(mv, part[s][ql]);
        const int qi = tile * QPB + ql;
        const float Qx = q[3 * qi + 0], Qy = q[3 * qi + 1], Qz = q[3 * qi + 2];
        ws_part[(size_t)bid * QPB + ql] = (Qx * Qx + Qy * Qy + Qz * Qz) + mv;
    }
}

// One block per batch: min over PSPLIT partials, threshold, double sum.
__global__ __launch_bounds__(QPB) void chamfer_finalize(
    const float* __restrict__ ws_part,
    const float* __restrict__ thp,
    float* __restrict__ out)
{
    __shared__ double wsum[QPB / 64];
    const int b = blockIdx.x;
    const float th = *thp;
    double acc = 0.0;
    for (int dir = 0; dir < 2; ++dir) {
        for (int t = 0; t < QTILES; ++t) {
            const size_t gb = ((size_t)((dir * NBATCH + b) * QTILES + t)) * PSPLIT;
            const int ql = threadIdx.x;
            float mv =            ws_part[(gb + 0) * QPB + ql];
            mv = fminf(mv, ws_part[(gb + 1) * QPB + ql]);
            mv = fminf(mv, ws_part[(gb + 2) * QPB + ql]);
            mv = fminf(mv, ws_part[(gb + 3) * QPB + ql]);
            acc += (mv <= th) ? 0.0 : (double)mv;
        }
    }
    for (int off = 32; off > 0; off >>= 1)
        acc += __shfl_down(acc, off, 64);
    const int lane = threadIdx.x & 63;
    const int w    = threadIdx.x >> 6;
    if (lane == 0) wsum[w] = acc;
    __syncthreads();
    if (threadIdx.x == 0) {
        double s = 0.0;
        #pragma unroll
        for (int i = 0; i < QPB / 64; ++i) s += wsum[i];
        out[b] = (float)(s / (double)NPTS);   // mean(d1)+mean(d2), N == M
    }
}

extern "C" void kernel_launch(void* const* d_in, const int* in_sizes, int n_in,
                              void* d_out, int out_size, void* d_ws, size_t ws_size,
                              hipStream_t stream) {
    const float* xyz1 = (const float*)d_in[0];
    const float* xyz2 = (const float*)d_in[1];
    const float* thp  = (const float*)d_in[2];
    float* out        = (float*)d_out;
    float* ws_part    = (float*)d_ws;   // NBLK*QPB*4 = 1 MiB scratch

    chamfer_main<<<NBLK, TPB, 0, stream>>>(xyz1, xyz2, ws_part);
    chamfer_finalize<<<NBATCH, QPB, 0, stream>>>(ws_part, thp, out);
}

// Round 5
// 49.161 us; speedup vs baseline: 1.2768x; 1.2768x over previous
//
#include <hip/hip_runtime.h>
#include <math.h>

#define NBATCH 4
#define NPTS   8192
#define TPB    512
#define NWAVE  (TPB / 64)                 // 8 waves
#define QPT    16                         // queries per lane
#define QPAIRS (QPT / 2)                  // 8 packed query pairs
#define QPB    (64 * QPT)                 // 1024 queries per block
#define QTILES (NPTS / QPB)               // 8 query tiles
#define PSPLIT 8                          // point-set split across blocks
#define PPB    (NPTS / PSPLIT)            // 1024 points staged per block
#define SLICE  (PPB / NWAVE)              // 128 points per wave
#define NBLK   (2 * NBATCH * QTILES * PSPLIT)  // 512 blocks = 2 per CU
#define NTILEB (2 * NBATCH * QTILES)      // 64 (dir,b,tile) groups

typedef float v2f __attribute__((ext_vector_type(2)));
typedef float v4f __attribute__((ext_vector_type(4)));

__device__ __forceinline__ float min3f(float a, float b, float c) {
    return fminf(fminf(a, b), c);         // -> v_min3_f32
}

// Block = (dir, batch, 1024-query tile, eighth of the point set).
// 1024 points staged in LDS SoA (-2x,-2y,-2z,||p||^2), 16 KiB. Wave w scans
// its 128-point slice; all 64 lanes read the same address (broadcast).
// Queries are packed as v2f PAIRS {qA,qB} (no splats -> no register blowup).
// Each LDS point-pair P={p0,p1} is consumed twice: straight (gives d(A,p0),
// d(B,p1)) and swapped (d(A,p1),d(B,p0)) -> 6 v_pk_fma_f32 + 2 v_min3_f32
// per 4 (query,point) pairs = 2.0 VALU instr/pair, and 1 ds_read_b128 per
// 64*16 pairs. qn is added after the min.
__global__ __launch_bounds__(TPB, 4) void chamfer_main(
    const float* __restrict__ xyz1,
    const float* __restrict__ xyz2,
    float* __restrict__ ws_part)
{
    __shared__ float sx[PPB] __attribute__((aligned(16)));
    __shared__ float sy[PPB] __attribute__((aligned(16)));
    __shared__ float sz[PPB] __attribute__((aligned(16)));
    __shared__ float sw[PPB] __attribute__((aligned(16)));
    __shared__ float part[NWAVE][QPB];    // 32 KiB slice partial mins

    const int bid  = blockIdx.x;
    const int ps   = bid & (PSPLIT - 1);
    const int r1   = bid >> 3;
    const int tile = r1 & (QTILES - 1);
    const int r2   = r1 >> 3;
    const int b    = r2 & (NBATCH - 1);
    const int dir  = r2 >> 2;             // 0: q=xyz1,r=xyz2; 1: swapped

    const float* q  = (dir == 0 ? xyz1 : xyz2) + (size_t)b * NPTS * 3;
    const float* rp = (dir == 0 ? xyz2 : xyz1) + (size_t)b * NPTS * 3
                      + (size_t)ps * PPB * 3;

    for (int i = threadIdx.x; i < PPB; i += TPB) {
        float x = rp[3 * i + 0], y = rp[3 * i + 1], z = rp[3 * i + 2];
        sx[i] = -2.0f * x;
        sy[i] = -2.0f * y;
        sz[i] = -2.0f * z;
        sw[i] = x * x + y * y + z * z;
    }
    __syncthreads();

    const int lane = threadIdx.x & 63;
    const int w    = threadIdx.x >> 6;
    const int q0   = tile * QPB + lane * QPT;

    v2f qx2[QPAIRS], qy2[QPAIRS], qz2[QPAIRS];
    float m[QPT];
    #pragma unroll
    for (int p = 0; p < QPAIRS; ++p) {
        const int iA = q0 + 2 * p, iB = iA + 1;
        qx2[p] = (v2f){ q[3 * iA + 0], q[3 * iB + 0] };
        qy2[p] = (v2f){ q[3 * iA + 1], q[3 * iB + 1] };
        qz2[p] = (v2f){ q[3 * iA + 2], q[3 * iB + 2] };
        m[2 * p] = INFINITY;
        m[2 * p + 1] = INFINITY;
    }

    const int base = w * SLICE;
    #pragma unroll 1
    for (int j = 0; j < SLICE; j += 8) {
        v4f X0 = *(const v4f*)&sx[base + j];
        v4f X1 = *(const v4f*)&sx[base + j + 4];
        v4f Y0 = *(const v4f*)&sy[base + j];
        v4f Y1 = *(const v4f*)&sy[base + j + 4];
        v4f Z0 = *(const v4f*)&sz[base + j];
        v4f Z1 = *(const v4f*)&sz[base + j + 4];
        v4f W0 = *(const v4f*)&sw[base + j];
        v4f W1 = *(const v4f*)&sw[base + j + 4];

        v2f Px[4] = { X0.lo, X0.hi, X1.lo, X1.hi };
        v2f Py[4] = { Y0.lo, Y0.hi, Y1.lo, Y1.hi };
        v2f Pz[4] = { Z0.lo, Z0.hi, Z1.lo, Z1.hi };
        v2f Pw[4] = { W0.lo, W0.hi, W1.lo, W1.hi };

        #pragma unroll
        for (int g = 0; g < 4; ++g) {
            const v2f xs = __builtin_shufflevector(Px[g], Px[g], 1, 0);
            const v2f ys = __builtin_shufflevector(Py[g], Py[g], 1, 0);
            const v2f zs = __builtin_shufflevector(Pz[g], Pz[g], 1, 0);
            const v2f wsw = __builtin_shufflevector(Pw[g], Pw[g], 1, 0);
            #pragma unroll
            for (int p = 0; p < QPAIRS; ++p) {
                v2f c1 = __builtin_elementwise_fma(qx2[p], Px[g],
                         __builtin_elementwise_fma(qy2[p], Py[g],
                         __builtin_elementwise_fma(qz2[p], Pz[g], Pw[g])));
                v2f c2 = __builtin_elementwise_fma(qx2[p], xs,
                         __builtin_elementwise_fma(qy2[p], ys,
                         __builtin_elementwise_fma(qz2[p], zs, wsw)));
                m[2 * p]     = min3f(m[2 * p],     c1.x, c2.x);
                m[2 * p + 1] = min3f(m[2 * p + 1], c1.y, c2.y);
            }
        }
    }

    // Swizzled store (stride-64B pattern would be a 32-way bank conflict).
    #pragma unroll
    for (int k = 0; k < QPT; ++k) {
        const int col = lane * QPT + ((k + lane) & (QPT - 1));
        part[w][col] = m[k];
    }
    __syncthreads();

    // Combine the 8 wave-slices per query, add qn, write block partial.
    for (int ql = threadIdx.x; ql < QPB; ql += TPB) {
        const int l   = ql >> 4;
        const int col = (ql & ~(QPT - 1)) | ((ql + l) & (QPT - 1));
        float mv = part[0][col];
        #pragma unroll
        for (int s = 1; s < NWAVE; ++s) mv = fminf(mv, part[s][col]);
        const int qi = tile * QPB + ql;
        const float Qx = q[3 * qi + 0], Qy = q[3 * qi + 1], Qz = q[3 * qi + 2];
        ws_part[(size_t)bid * QPB + ql] = (Qx * Qx + Qy * Qy + Qz * Qz) + mv;
    }
}

// 64 blocks = one per (dir,b,tile): min over PSPLIT partials, threshold,
// per-tile double sum -> tile_sums.
__global__ __launch_bounds__(256) void chamfer_finalize1(
    const float* __restrict__ ws_part,
    const float* __restrict__ thp,
    double* __restrict__ tile_sums)
{
    __shared__ double wsum[4];
    const int t = blockIdx.x;             // t = ((dir*4+b)*8+tile)
    const float th = *thp;
    const size_t gb = (size_t)t * PSPLIT;
    double acc = 0.0;
    for (int ql = threadIdx.x; ql < QPB; ql += 256) {
        float mv = ws_part[(gb + 0) * QPB + ql];
        #pragma unroll
        for (int s = 1; s < PSPLIT; ++s)
            mv = fminf(mv, ws_part[(gb + s) * QPB + ql]);
        acc += (mv <= th) ? 0.0 : (double)mv;
    }
    for (int off = 32; off > 0; off >>= 1)
        acc += __shfl_down(acc, off, 64);
    const int lane = threadIdx.x & 63;
    const int w    = threadIdx.x >> 6;
    if (lane == 0) wsum[w] = acc;
    __syncthreads();
    if (threadIdx.x == 0) {
        double s = wsum[0] + wsum[1] + wsum[2] + wsum[3];
        tile_sums[t] = s;
    }
}

__global__ void chamfer_finalize2(const double* __restrict__ tile_sums,
                                  float* __restrict__ out)
{
    const int b = threadIdx.x;
    if (b < NBATCH) {
        double s = 0.0;
        for (int dir = 0; dir < 2; ++dir)
            for (int t = 0; t < QTILES; ++t)
                s += tile_sums[(dir * NBATCH + b) * QTILES + t];
        out[b] = (float)(s / (double)NPTS);   // mean(d1)+mean(d2), N == M
    }
}

extern "C" void kernel_launch(void* const* d_in, const int* in_sizes, int n_in,
                              void* d_out, int out_size, void* d_ws, size_t ws_size,
                              hipStream_t stream) {
    const float* xyz1 = (const float*)d_in[0];
    const float* xyz2 = (const float*)d_in[1];
    const float* thp  = (const float*)d_in[2];
    float* out        = (float*)d_out;
    float* ws_part    = (float*)d_ws;                       // 512*1024*4 = 2 MiB
    double* tile_sums = (double*)(ws_part + NBLK * QPB);    // + 64*8 B

    chamfer_main<<<NBLK, TPB, 0, stream>>>(xyz1, xyz2, ws_part);
    chamfer_finalize1<<<NTILEB, 256, 0, stream>>>(ws_part, thp, tile_sums);
    chamfer_finalize2<<<1, 64, 0, stream>>>(tile_sums, out);
}